// Round 13
// baseline (348.650 us; speedup 1.0000x reference)
//
#include <hip/hip_runtime.h>
#include <math.h>

#define NODES 20000
#define MPAD  20096          // NODES padded to multiple of 128 (GEMM M-tiles)
#define EDGES 320000
#define EPSV  1e-5f
#define LOG2E 1.4426950408889634f

// k_prep block ranges
#define PREP_CNT   1250                    // count: 1250*256 >= EDGES
#define PREP_CAST  5000                    // cast: NODES*256/4/256
#define PREP_TR    512                     // 4 matrices * 128 tiles
#define PREP_TOTAL (PREP_CNT + PREP_CAST + PREP_TR + 1)

typedef short bf16x8 __attribute__((ext_vector_type(8)));
typedef float f32x4  __attribute__((ext_vector_type(4)));
typedef float f2     __attribute__((ext_vector_type(2)));

__device__ __forceinline__ unsigned short f2bf(float f) {
    unsigned int u = __float_as_uint(f);
    u = (u + 0x7fffu + ((u >> 16) & 1u)) >> 16;
    return (unsigned short)u;
}
__device__ __forceinline__ float bf2f(unsigned short h) {
    return __uint_as_float(((unsigned int)h) << 16);
}

// async global->LDS, 16B per lane; lds dest = wave-uniform base + lane*16
__device__ __forceinline__ void load_lds16(const unsigned short* g, unsigned short* l) {
    __builtin_amdgcn_global_load_lds(
        (const __attribute__((address_space(1))) unsigned int*)g,
        (__attribute__((address_space(3))) unsigned int*)l, 16, 0, 0);
}

// ---------------- fused prep: edge-count + x cast + 4x weight transpose + zeros
__global__ void k_prep(const int* __restrict__ dst, int* __restrict__ counts,
                       const float* __restrict__ x, unsigned short* __restrict__ xb,
                       const float* __restrict__ Wl1, const float* __restrict__ Wr1,
                       const float* __restrict__ Wl2, const float* __restrict__ Wr2,
                       unsigned short* __restrict__ o1l, unsigned short* __restrict__ o1r,
                       unsigned short* __restrict__ o2l, unsigned short* __restrict__ o2r,
                       float* __restrict__ acc, float* __restrict__ colsum) {
    int b = blockIdx.x;
    int t = threadIdx.x;
    if (b < PREP_CNT) {
        int e = b * 256 + t;
        if (e < EDGES) atomicAdd(&counts[dst[e]], 1);
    } else if (b < PREP_CNT + PREP_CAST) {
        int i = ((b - PREP_CNT) * 256 + t) * 4;
        float4 v = *(const float4*)(x + i);
        xb[i + 0] = f2bf(v.x); xb[i + 1] = f2bf(v.y);
        xb[i + 2] = f2bf(v.z); xb[i + 3] = f2bf(v.w);
    } else if (b < PREP_CNT + PREP_CAST + PREP_TR) {
        __shared__ float tile[32][33];
        int zz = b - PREP_CNT - PREP_CAST;     // 0..511
        int z = zz >> 7;                        // matrix 0..3
        int idx = zz & 127;                     // tile within matrix
        const float* W = (z == 0) ? Wl1 : (z == 1) ? Wr1 : (z == 2) ? Wl2 : Wr2;
        unsigned short* Wt = (z == 0) ? o1l : (z == 1) ? o1r : (z == 2) ? o2l : o2r;
        int K = (z < 2) ? 256 : 512, N = (z < 2) ? 512 : 256;
        int nb = N / 32;
        int n0 = (idx % nb) * 32, k0 = (idx / nb) * 32;
        int tx = t & 31, ty = t >> 5;          // (32,8) layout
#pragma unroll
        for (int j = 0; j < 4; j++)
            tile[ty + j * 8][tx] = W[(size_t)(k0 + ty + j * 8) * N + n0 + tx];
        __syncthreads();
#pragma unroll
        for (int j = 0; j < 4; j++)
            Wt[(size_t)(n0 + ty + j * 8) * K + k0 + tx] = f2bf(tile[tx][ty + j * 8]);
    } else {
        if (t < 4) acc[t] = 0.f;
        colsum[t] = 0.f;
    }
}

// ---------------- CSR scan + scatter ----------------
__global__ void k_scan(const int* __restrict__ counts, int* __restrict__ offs) {
    __shared__ int ssum[256];
    int t = threadIdx.x;
    const int chunk = (NODES + 255) / 256;
    int b = t * chunk, e = b + chunk;
    if (b > NODES) b = NODES;
    if (e > NODES) e = NODES;
    int s = 0;
    for (int i = b; i < e; i++) s += counts[i];
    ssum[t] = s;
    __syncthreads();
    int v = s;
#pragma unroll
    for (int o = 1; o < 256; o <<= 1) {
        int add = (t >= o) ? ssum[t - o] : 0;
        __syncthreads();
        v += add;
        ssum[t] = v;
        __syncthreads();
    }
    int run = v - s;
    if (t == 255) offs[NODES] = v;
    for (int i = b; i < e; i++) { offs[i] = run; run += counts[i]; }
}

__global__ void k_scatter(const int* __restrict__ src, const int* __restrict__ dst,
                          const int* __restrict__ offs, int* __restrict__ cursor,
                          int* __restrict__ csr_src) {
    int e = blockIdx.x * blockDim.x + threadIdx.x;
    if (e < EDGES) {
        int d = dst[e];
        int pos = atomicAdd(&cursor[d], 1);
        csr_src[offs[d] + pos] = src[e];
    }
}

// ------- per-channel softmax aggregation, un-stabilized (inputs bounded) -----
// S waves per node (interleaved waveg%S — measured fastest agg variant, r10).
// Wave-uniform CSR walk via readfirstlane: csr[k] -> s_load; vector pipe:
// loop-invariant-offset gather + packed-f32 exp2/fma.
template <int C, int S, int UNR>
__global__ void k_agg(const unsigned short* __restrict__ xb, const float* __restrict__ tt,
                      const int* __restrict__ offs, const int* __restrict__ csr,
                      unsigned short* __restrict__ out) {
    constexpr int CS  = C / S;
    constexpr int VPL = CS / 64;
    constexpr int W   = VPL / 2;
    typedef unsigned int uv __attribute__((ext_vector_type(W)));
    typedef unsigned short usv __attribute__((ext_vector_type(VPL)));
    int waveg = (int)((blockIdx.x * (unsigned)blockDim.x + threadIdx.x) >> 6);
    int lane = threadIdx.x & 63;
    int node = waveg / S;
    int slice = waveg % S;
    if (node >= NODES) return;
    int beg = __builtin_amdgcn_readfirstlane(offs[node]);
    int end = __builtin_amdgcn_readfirstlane(offs[node + 1]);
    int cb = slice * CS + lane * VPL;
    const unsigned short* __restrict__ xcb = xb + cb;
    f2 tl[W], l[W], s[W];
#pragma unroll
    for (int i = 0; i < W; i++) {
        tl[i][0] = tt[cb + 2 * i] * LOG2E;
        tl[i][1] = tt[cb + 2 * i + 1] * LOG2E;
        l[i][0] = 0.f; l[i][1] = 0.f;
        s[i][0] = 0.f; s[i][1] = 0.f;
    }
    int k = beg;
    for (; k + UNR <= end; k += UNR) {
        uv v[UNR];
#pragma unroll
        for (int u = 0; u < UNR; u++) {
            int sn = csr[k + u];                     // uniform -> s_load
            v[u] = *(const uv*)(xcb + (size_t)sn * C);
        }
#pragma unroll
        for (int u = 0; u < UNR; u++)
#pragma unroll
            for (int i = 0; i < W; i++) {
                unsigned wd = v[u][i];
                f2 xv;
                xv[0] = __uint_as_float(wd << 16);
                xv[1] = __uint_as_float(wd & 0xffff0000u);
                f2 a = xv * tl[i];
                f2 p;
                p[0] = __builtin_amdgcn_exp2f(a[0]);
                p[1] = __builtin_amdgcn_exp2f(a[1]);
                l[i] += p;
                s[i] = __builtin_elementwise_fma(p, xv, s[i]);
            }
    }
    for (; k < end; k++) {
        int sn = csr[k];
        uv vv = *(const uv*)(xcb + (size_t)sn * C);
#pragma unroll
        for (int i = 0; i < W; i++) {
            unsigned wd = vv[i];
            f2 xv;
            xv[0] = __uint_as_float(wd << 16);
            xv[1] = __uint_as_float(wd & 0xffff0000u);
            f2 a = xv * tl[i];
            f2 p;
            p[0] = __builtin_amdgcn_exp2f(a[0]);
            p[1] = __builtin_amdgcn_exp2f(a[1]);
            l[i] += p;
            s[i] = __builtin_elementwise_fma(p, xv, s[i]);
        }
    }
    bool has = end > beg;
    usv o;
#pragma unroll
    for (int i = 0; i < W; i++) {
        o[2 * i]     = f2bf(has ? s[i][0] / l[i][0] : 0.f);
        o[2 * i + 1] = f2bf(has ? s[i][1] / l[i][1] : 0.f);
    }
    *(usv*)(out + (size_t)node * C + cb) = o;
}

// ---------------- dual bf16 MFMA GEMM: C = A1*B1t^T + A2*B2t^T + bias ---------
// Tile 128 x TN (TN=128 or 64). TN=64 doubles block count for small-N GEMMs
// (gemm2: 314 -> 628 blocks = 2.4/CU, restoring inter-block barrier overlap).
// 1D grid, XCD-affinity swizzle: all NTILES n-variants of one m-tile map to the
// same bx%8 (=XCD) so the re-staged A-tile stays L2-resident. BK=32 LDS layout
// (measured conflict-free). LN sum/sumsq fused into epilogue.
template <int K, int NT, int NTILES, int TN>
__global__ __launch_bounds__(256) void k_gemm_mfma(
    const unsigned short* __restrict__ A1, const unsigned short* __restrict__ B1t,
    const unsigned short* __restrict__ A2, const unsigned short* __restrict__ B2t,
    const float* __restrict__ bias, unsigned short* __restrict__ Co, int M,
    float* __restrict__ stat) {
    constexpr int NF = TN / 32;            // n-frags per wave (2 waves span TN)
    __shared__ short As[128 * 32];
    __shared__ short Bs[TN * 32];
    __shared__ float rs[256], rq[256];

    // swizzled decode: bx = x + 8*(n + NTILES*mh); m = mh*8 + x
    int bx = blockIdx.x;
    int xid = bx & 7, q = bx >> 3;
    int n = q % NTILES, mh = q / NTILES;
    int m = mh * 8 + xid;
    if (m * 128 >= MPAD) return;           // pad tiles: whole block exits
    int m0 = m * 128, n0 = n * TN;

    int t = threadIdx.x;
    int wv = t >> 6, lane = t & 63;
    int wm = wv & 1, wn = wv >> 1;
    int lm = lane & 15, quad = lane >> 4;
    int sr = t >> 2;
    int sc8 = (t & 3) * 8;

    f32x4 acc[4][NF] = {};

    for (int ph = 0; ph < 2; ph++) {
        const unsigned short* __restrict__ A  = ph ? A2 : A1;
        const unsigned short* __restrict__ Bt = ph ? B2t : B1t;
        for (int k0 = 0; k0 < K; k0 += 32) {
#pragma unroll
            for (int it = 0; it < 2; it++)
                load_lds16(A + (size_t)(m0 + it * 64 + sr) * K + k0 + sc8,
                           (unsigned short*)&As[it * 2048 + wv * 512]);
#pragma unroll
            for (int it = 0; it < TN / 64; it++)
                load_lds16(Bt + (size_t)(n0 + it * 64 + sr) * K + k0 + sc8,
                           (unsigned short*)&Bs[it * 2048 + wv * 512]);
            __syncthreads();
            bf16x8 af[4], bfr[NF];
#pragma unroll
            for (int i = 0; i < 4; i++)
                af[i] = *(const bf16x8*)&As[(wm * 64 + i * 16 + lm) * 32 + quad * 8];
#pragma unroll
            for (int j = 0; j < NF; j++)
                bfr[j] = *(const bf16x8*)&Bs[(wn * (TN / 2) + j * 16 + lm) * 32 + quad * 8];
#pragma unroll
            for (int mi = 0; mi < 4; mi++)
#pragma unroll
                for (int nj = 0; nj < NF; nj++)
                    acc[mi][nj] = __builtin_amdgcn_mfma_f32_16x16x32_bf16(
                        af[mi], bfr[nj], acc[mi][nj], 0, 0, 0);
            __syncthreads();
        }
    }

    float sum = 0.f, ss = 0.f;
#pragma unroll
    for (int mi = 0; mi < 4; mi++) {
        int rb = m0 + wm * 64 + mi * 16 + quad * 4;
#pragma unroll
        for (int nj = 0; nj < NF; nj++) {
            int col = n0 + wn * (TN / 2) + nj * 16 + lm;
            float bb = bias[col];
#pragma unroll
            for (int rg = 0; rg < 4; rg++) {
                int row = rb + rg;
                if (row < M) {
                    float y = acc[mi][nj][rg] + bb;
                    Co[(size_t)row * NT + col] = f2bf(y);
                    sum += y; ss += y * y;
                }
            }
        }
    }
    rs[t] = sum; rq[t] = ss;
    __syncthreads();
    for (int o = 128; o > 0; o >>= 1) {
        if (t < o) { rs[t] += rs[t + o]; rq[t] += rq[t + o]; }
        __syncthreads();
    }
    if (t == 0) { atomicAdd(&stat[0], rs[0]); atomicAdd(&stat[1], rq[0]); }
}

// ---------------- graph-LN + ReLU, in-place bf16, vectorized x8 --------------
template <int C>
__global__ void k_ln_relu_b(unsigned short* __restrict__ h, int n,
                            const float* __restrict__ st,
                            const float* __restrict__ g, const float* __restrict__ b) {
    typedef unsigned short us8 __attribute__((ext_vector_type(8)));
    float mu = st[0] / (float)n;
    float var = st[1] / (float)n - mu * mu;
    var = var < 0.f ? 0.f : var;
    float inv = 1.0f / (sqrtf(var) + EPSV);
    int i8 = (blockIdx.x * blockDim.x + threadIdx.x) * 8;
    if (i8 >= n) return;
    int c = i8 & (C - 1);
    us8 v = *(const us8*)(h + i8);
    us8 o;
#pragma unroll
    for (int j = 0; j < 8; j++) {
        float y = (bf2f(v[j]) - mu) * inv * g[c + j] + b[c + j];
        o[j] = f2bf(fmaxf(y, 0.f));
    }
    *(us8*)(h + i8) = o;
}

// graph-LN + ReLU + column-sum only (layer 2; h2 not needed afterwards)
__global__ void k_ln_colsum(const unsigned short* __restrict__ h, int n,
                            const float* __restrict__ st,
                            const float* __restrict__ g, const float* __restrict__ b,
                            float* __restrict__ colsum) {
    float mu = st[0] / (float)n;
    float var = st[1] / (float)n - mu * mu;
    var = var < 0.f ? 0.f : var;
    float inv = 1.0f / (sqrtf(var) + EPSV);
    int t = threadIdx.x;
    float gv = g[t], bv = b[t];
    float local = 0.f;
    int stride = gridDim.x * blockDim.x;   // multiple of 256 -> channel == t always
    for (int i = blockIdx.x * blockDim.x + t; i < n; i += stride) {
        float y = (bf2f(h[i]) - mu) * inv * gv + bv;
        local += fmaxf(y, 0.f);
    }
    atomicAdd(&colsum[t], local);
}

// ---------------- head: mean-pool @ Wf + bf -> LN(64) -> relu ----------------
__global__ void k_final(const float* __restrict__ colsum, const float* __restrict__ Wf,
                        const float* __restrict__ bf, const float* __restrict__ gx,
                        const float* __restrict__ bx, float* __restrict__ out) {
    __shared__ float p[256];
    int t = threadIdx.x;
    p[t] = colsum[t] * (1.0f / (float)NODES);
    __syncthreads();
    if (t < 64) {
        float acc = bf[t];
        for (int c = 0; c < 256; c++) acc = fmaf(p[c], Wf[c * 64 + t], acc);
        float sum = acc;
        for (int o = 32; o > 0; o >>= 1) sum += __shfl_xor(sum, o);
        float mu = sum * (1.0f / 64.0f);
        float d = acc - mu;
        float vs = d * d;
        for (int o = 32; o > 0; o >>= 1) vs += __shfl_xor(vs, o);
        float var = vs * (1.0f / 64.0f);
        float y = d * rsqrtf(var + EPSV) * gx[t] + bx[t];
        out[t] = fmaxf(y, 0.f);
    }
}

extern "C" void kernel_launch(void* const* d_in, const int* in_sizes, int n_in,
                              void* d_out, int out_size, void* d_ws, size_t ws_size,
                              hipStream_t stream) {
    const float* x   = (const float*)d_in[0];
    const int*   ei  = (const int*)d_in[1];
    const float* t1  = (const float*)d_in[2];
    const float* Wl1 = (const float*)d_in[3];
    const float* bl1 = (const float*)d_in[4];
    const float* Wr1 = (const float*)d_in[5];
    const float* g1  = (const float*)d_in[6];
    const float* be1 = (const float*)d_in[7];
    const float* t2  = (const float*)d_in[8];
    const float* Wl2 = (const float*)d_in[9];
    const float* bl2 = (const float*)d_in[10];
    const float* Wr2 = (const float*)d_in[11];
    const float* g2  = (const float*)d_in[12];
    const float* be2 = (const float*)d_in[13];
    const float* Wf  = (const float*)d_in[14];
    const float* bf  = (const float*)d_in[15];
    const float* gx  = (const float*)d_in[16];
    const float* bx  = (const float*)d_in[17];
    float* out = (float*)d_out;

    char* ws = (char*)d_ws;
    size_t off = 0;
    auto alloc = [&](size_t bytes) { size_t o = off; off = (off + bytes + 511) & ~511ull; return o; };
    size_t o_counts = alloc((size_t)NODES * 4);
    size_t o_cursor = alloc((size_t)NODES * 4);
    size_t zero_bytes = off;                         // memset: counts+cursor only
    size_t o_acc    = alloc(4 * 4);
    size_t o_colsum = alloc(256 * 4);
    size_t o_offs = alloc((size_t)(NODES + 1) * 4);
    size_t o_csrc = alloc((size_t)EDGES * 4);
    size_t o_w1l  = alloc((size_t)512 * 256 * 2);
    size_t o_w1r  = alloc((size_t)512 * 256 * 2);
    size_t o_w2l  = alloc((size_t)256 * 512 * 2);
    size_t o_w2r  = alloc((size_t)256 * 512 * 2);
    size_t o_bufX = alloc((size_t)MPAD * 256 * 2);   // xb, later h2_pre (bf16)
    size_t o_agg  = alloc((size_t)MPAD * 512 * 2);   // agg1b / agg2b
    size_t o_h1   = alloc((size_t)(MPAD + 512) * 512 * 2); // h1 (+pad-tile slack)

    int*   counts = (int*)(ws + o_counts);
    int*   cursor = (int*)(ws + o_cursor);
    float* acc    = (float*)(ws + o_acc);      // [0,1]=L1 stats, [2,3]=L2 stats
    float* colsum = (float*)(ws + o_colsum);
    int*   offs   = (int*)(ws + o_offs);
    int*   csrc   = (int*)(ws + o_csrc);
    unsigned short* w1lt = (unsigned short*)(ws + o_w1l);
    unsigned short* w1rt = (unsigned short*)(ws + o_w1r);
    unsigned short* w2lt = (unsigned short*)(ws + o_w2l);
    unsigned short* w2rt = (unsigned short*)(ws + o_w2r);
    unsigned short* xb   = (unsigned short*)(ws + o_bufX);
    unsigned short* h2p  = (unsigned short*)(ws + o_bufX);  // reuse after xb dead
    unsigned short* aggb = (unsigned short*)(ws + o_agg);
    unsigned short* h1   = (unsigned short*)(ws + o_h1);

    const int* src = ei;
    const int* dst = ei + EDGES;

    hipMemsetAsync(ws, 0, zero_bytes, stream);

    // D1: fused prep (count + cast + transposes + zero acc/colsum)
    k_prep<<<PREP_TOTAL, 256, 0, stream>>>(dst, counts, x, xb,
                                           Wl1, Wr1, Wl2, Wr2,
                                           w1lt, w1rt, w2lt, w2rt,
                                           acc, colsum);
    // D2/D3: CSR
    k_scan<<<1, 256, 0, stream>>>(counts, offs);
    k_scatter<<<(EDGES + 255) / 256, 256, 0, stream>>>(src, dst, offs, cursor, csrc);

    // ----- layer 1 -----  (2 waves per node, 128 ch each)
    k_agg<256, 2, 8><<<(NODES * 2 + 3) / 4, 256, 0, stream>>>(xb, t1, offs, csrc, aggb);
    k_gemm_mfma<256, 512, 4, 128><<<8 * 4 * 20, 256, 0, stream>>>(
        aggb, w1lt, xb, w1rt, bl1, h1, NODES, acc);
    k_ln_relu_b<512><<<NODES * 512 / 8 / 256, 256, 0, stream>>>(h1, NODES * 512, acc, g1, be1);

    // ----- layer 2 -----  (2 waves per node, 256 ch each)
    k_agg<512, 2, 4><<<(NODES * 2 + 3) / 4, 256, 0, stream>>>(h1, t2, offs, csrc, aggb);
    k_gemm_mfma<512, 256, 4, 64><<<8 * 4 * 20, 256, 0, stream>>>(
        aggb, w2lt, h1, w2rt, bl2, h2p, NODES, acc + 2);

    // ----- LN2 + colsum, then head -----
    k_ln_colsum<<<1024, 256, 0, stream>>>(h2p, NODES * 256, acc + 2, g2, be2, colsum);
    k_final<<<1, 256, 0, stream>>>(colsum, Wf, bf, gx, bx, out);
}

// Round 14
// 345.764 us; speedup vs baseline: 1.0083x; 1.0083x over previous
//
#include <hip/hip_runtime.h>
#include <math.h>

#define NODES 20000
#define MPAD  20096          // NODES padded to multiple of 128 (GEMM M-tiles)
#define EDGES 320000
#define EPSV  1e-5f
#define LOG2E 1.4426950408889634f

// k_prep block ranges
#define PREP_CNT   1250                    // count: 1250*256 >= EDGES
#define PREP_CAST  5000                    // cast: NODES*256/4/256
#define PREP_TR    512                     // 4 matrices * 128 tiles
#define PREP_TOTAL (PREP_CNT + PREP_CAST + PREP_TR + 1)

typedef short bf16x8 __attribute__((ext_vector_type(8)));
typedef float f32x4  __attribute__((ext_vector_type(4)));
typedef float f2     __attribute__((ext_vector_type(2)));

__device__ __forceinline__ unsigned short f2bf(float f) {
    unsigned int u = __float_as_uint(f);
    u = (u + 0x7fffu + ((u >> 16) & 1u)) >> 16;
    return (unsigned short)u;
}
__device__ __forceinline__ float bf2f(unsigned short h) {
    return __uint_as_float(((unsigned int)h) << 16);
}

// async global->LDS, 16B per lane; lds dest = wave-uniform base + lane*16
__device__ __forceinline__ void load_lds16(const unsigned short* g, unsigned short* l) {
    __builtin_amdgcn_global_load_lds(
        (const __attribute__((address_space(1))) unsigned int*)g,
        (__attribute__((address_space(3))) unsigned int*)l, 16, 0, 0);
}

// ---------------- fused prep: edge-count + x cast + 4x weight transpose + zeros
__global__ void k_prep(const int* __restrict__ dst, int* __restrict__ counts,
                       const float* __restrict__ x, unsigned short* __restrict__ xb,
                       const float* __restrict__ Wl1, const float* __restrict__ Wr1,
                       const float* __restrict__ Wl2, const float* __restrict__ Wr2,
                       unsigned short* __restrict__ o1l, unsigned short* __restrict__ o1r,
                       unsigned short* __restrict__ o2l, unsigned short* __restrict__ o2r,
                       float* __restrict__ acc, float* __restrict__ colsum) {
    int b = blockIdx.x;
    int t = threadIdx.x;
    if (b < PREP_CNT) {
        int e = b * 256 + t;
        if (e < EDGES) atomicAdd(&counts[dst[e]], 1);
    } else if (b < PREP_CNT + PREP_CAST) {
        int i = ((b - PREP_CNT) * 256 + t) * 4;
        float4 v = *(const float4*)(x + i);
        xb[i + 0] = f2bf(v.x); xb[i + 1] = f2bf(v.y);
        xb[i + 2] = f2bf(v.z); xb[i + 3] = f2bf(v.w);
    } else if (b < PREP_CNT + PREP_CAST + PREP_TR) {
        __shared__ float tile[32][33];
        int zz = b - PREP_CNT - PREP_CAST;     // 0..511
        int z = zz >> 7;                        // matrix 0..3
        int idx = zz & 127;                     // tile within matrix
        const float* W = (z == 0) ? Wl1 : (z == 1) ? Wr1 : (z == 2) ? Wl2 : Wr2;
        unsigned short* Wt = (z == 0) ? o1l : (z == 1) ? o1r : (z == 2) ? o2l : o2r;
        int K = (z < 2) ? 256 : 512, N = (z < 2) ? 512 : 256;
        int nb = N / 32;
        int n0 = (idx % nb) * 32, k0 = (idx / nb) * 32;
        int tx = t & 31, ty = t >> 5;          // (32,8) layout
#pragma unroll
        for (int j = 0; j < 4; j++)
            tile[ty + j * 8][tx] = W[(size_t)(k0 + ty + j * 8) * N + n0 + tx];
        __syncthreads();
#pragma unroll
        for (int j = 0; j < 4; j++)
            Wt[(size_t)(n0 + ty + j * 8) * K + k0 + tx] = f2bf(tile[tx][ty + j * 8]);
    } else {
        if (t < 4) acc[t] = 0.f;
        colsum[t] = 0.f;
    }
}

// ---------------- CSR scan + scatter ----------------
__global__ void k_scan(const int* __restrict__ counts, int* __restrict__ offs) {
    __shared__ int ssum[256];
    int t = threadIdx.x;
    const int chunk = (NODES + 255) / 256;
    int b = t * chunk, e = b + chunk;
    if (b > NODES) b = NODES;
    if (e > NODES) e = NODES;
    int s = 0;
    for (int i = b; i < e; i++) s += counts[i];
    ssum[t] = s;
    __syncthreads();
    int v = s;
#pragma unroll
    for (int o = 1; o < 256; o <<= 1) {
        int add = (t >= o) ? ssum[t - o] : 0;
        __syncthreads();
        v += add;
        ssum[t] = v;
        __syncthreads();
    }
    int run = v - s;
    if (t == 255) offs[NODES] = v;
    for (int i = b; i < e; i++) { offs[i] = run; run += counts[i]; }
}

__global__ void k_scatter(const int* __restrict__ src, const int* __restrict__ dst,
                          const int* __restrict__ offs, int* __restrict__ cursor,
                          int* __restrict__ csr_src) {
    int e = blockIdx.x * blockDim.x + threadIdx.x;
    if (e < EDGES) {
        int d = dst[e];
        int pos = atomicAdd(&cursor[d], 1);
        csr_src[offs[d] + pos] = src[e];
    }
}

// ------- per-channel softmax aggregation, un-stabilized (inputs bounded) -----
// S waves per node (interleaved waveg%S — measured fastest agg variant, r10).
// Wave-uniform CSR walk via readfirstlane: csr[k] -> s_load; vector pipe:
// loop-invariant-offset gather + packed-f32 exp2/fma.
// Measured floor ~44.5us (layer 2): 6 structural variants all land 44-50us.
template <int C, int S, int UNR>
__global__ void k_agg(const unsigned short* __restrict__ xb, const float* __restrict__ tt,
                      const int* __restrict__ offs, const int* __restrict__ csr,
                      unsigned short* __restrict__ out) {
    constexpr int CS  = C / S;
    constexpr int VPL = CS / 64;
    constexpr int W   = VPL / 2;
    typedef unsigned int uv __attribute__((ext_vector_type(W)));
    typedef unsigned short usv __attribute__((ext_vector_type(VPL)));
    int waveg = (int)((blockIdx.x * (unsigned)blockDim.x + threadIdx.x) >> 6);
    int lane = threadIdx.x & 63;
    int node = waveg / S;
    int slice = waveg % S;
    if (node >= NODES) return;
    int beg = __builtin_amdgcn_readfirstlane(offs[node]);
    int end = __builtin_amdgcn_readfirstlane(offs[node + 1]);
    int cb = slice * CS + lane * VPL;
    const unsigned short* __restrict__ xcb = xb + cb;
    f2 tl[W], l[W], s[W];
#pragma unroll
    for (int i = 0; i < W; i++) {
        tl[i][0] = tt[cb + 2 * i] * LOG2E;
        tl[i][1] = tt[cb + 2 * i + 1] * LOG2E;
        l[i][0] = 0.f; l[i][1] = 0.f;
        s[i][0] = 0.f; s[i][1] = 0.f;
    }
    int k = beg;
    for (; k + UNR <= end; k += UNR) {
        uv v[UNR];
#pragma unroll
        for (int u = 0; u < UNR; u++) {
            int sn = csr[k + u];                     // uniform -> s_load
            v[u] = *(const uv*)(xcb + (size_t)sn * C);
        }
#pragma unroll
        for (int u = 0; u < UNR; u++)
#pragma unroll
            for (int i = 0; i < W; i++) {
                unsigned wd = v[u][i];
                f2 xv;
                xv[0] = __uint_as_float(wd << 16);
                xv[1] = __uint_as_float(wd & 0xffff0000u);
                f2 a = xv * tl[i];
                f2 p;
                p[0] = __builtin_amdgcn_exp2f(a[0]);
                p[1] = __builtin_amdgcn_exp2f(a[1]);
                l[i] += p;
                s[i] = __builtin_elementwise_fma(p, xv, s[i]);
            }
    }
    for (; k < end; k++) {
        int sn = csr[k];
        uv vv = *(const uv*)(xcb + (size_t)sn * C);
#pragma unroll
        for (int i = 0; i < W; i++) {
            unsigned wd = vv[i];
            f2 xv;
            xv[0] = __uint_as_float(wd << 16);
            xv[1] = __uint_as_float(wd & 0xffff0000u);
            f2 a = xv * tl[i];
            f2 p;
            p[0] = __builtin_amdgcn_exp2f(a[0]);
            p[1] = __builtin_amdgcn_exp2f(a[1]);
            l[i] += p;
            s[i] = __builtin_elementwise_fma(p, xv, s[i]);
        }
    }
    bool has = end > beg;
    usv o;
#pragma unroll
    for (int i = 0; i < W; i++) {
        o[2 * i]     = f2bf(has ? s[i][0] / l[i][0] : 0.f);
        o[2 * i + 1] = f2bf(has ? s[i][1] / l[i][1] : 0.f);
    }
    *(usv*)(out + (size_t)node * C + cb) = o;
}

// ---------------- dual bf16 MFMA GEMM: C = A1*B1t^T + A2*B2t^T + bias ---------
// Tile 128x128 (TN=64 measured slightly WORSE for gemm2 — r13). 1D grid with
// XCD-affinity swizzle: all NTILES n-variants of one m-tile map to the same
// bx%8 (=XCD) so the re-staged A-tile stays L2-resident. BK=32 LDS layout
// (measured conflict-free). LN sum/sumsq fused into epilogue.
template <int K, int NT, int NTILES, int TN>
__global__ __launch_bounds__(256) void k_gemm_mfma(
    const unsigned short* __restrict__ A1, const unsigned short* __restrict__ B1t,
    const unsigned short* __restrict__ A2, const unsigned short* __restrict__ B2t,
    const float* __restrict__ bias, unsigned short* __restrict__ Co, int M,
    float* __restrict__ stat) {
    constexpr int NF = TN / 32;            // n-frags per wave (2 waves span TN)
    __shared__ short As[128 * 32];
    __shared__ short Bs[TN * 32];
    __shared__ float rs[256], rq[256];

    // swizzled decode: bx = x + 8*(n + NTILES*mh); m = mh*8 + x
    int bx = blockIdx.x;
    int xid = bx & 7, q = bx >> 3;
    int n = q % NTILES, mh = q / NTILES;
    int m = mh * 8 + xid;
    if (m * 128 >= MPAD) return;           // pad tiles: whole block exits
    int m0 = m * 128, n0 = n * TN;

    int t = threadIdx.x;
    int wv = t >> 6, lane = t & 63;
    int wm = wv & 1, wn = wv >> 1;
    int lm = lane & 15, quad = lane >> 4;
    int sr = t >> 2;
    int sc8 = (t & 3) * 8;

    f32x4 acc[4][NF] = {};

    for (int ph = 0; ph < 2; ph++) {
        const unsigned short* __restrict__ A  = ph ? A2 : A1;
        const unsigned short* __restrict__ Bt = ph ? B2t : B1t;
        for (int k0 = 0; k0 < K; k0 += 32) {
#pragma unroll
            for (int it = 0; it < 2; it++)
                load_lds16(A + (size_t)(m0 + it * 64 + sr) * K + k0 + sc8,
                           (unsigned short*)&As[it * 2048 + wv * 512]);
#pragma unroll
            for (int it = 0; it < TN / 64; it++)
                load_lds16(Bt + (size_t)(n0 + it * 64 + sr) * K + k0 + sc8,
                           (unsigned short*)&Bs[it * 2048 + wv * 512]);
            __syncthreads();
            bf16x8 af[4], bfr[NF];
#pragma unroll
            for (int i = 0; i < 4; i++)
                af[i] = *(const bf16x8*)&As[(wm * 64 + i * 16 + lm) * 32 + quad * 8];
#pragma unroll
            for (int j = 0; j < NF; j++)
                bfr[j] = *(const bf16x8*)&Bs[(wn * (TN / 2) + j * 16 + lm) * 32 + quad * 8];
#pragma unroll
            for (int mi = 0; mi < 4; mi++)
#pragma unroll
                for (int nj = 0; nj < NF; nj++)
                    acc[mi][nj] = __builtin_amdgcn_mfma_f32_16x16x32_bf16(
                        af[mi], bfr[nj], acc[mi][nj], 0, 0, 0);
            __syncthreads();
        }
    }

    float sum = 0.f, ss = 0.f;
#pragma unroll
    for (int mi = 0; mi < 4; mi++) {
        int rb = m0 + wm * 64 + mi * 16 + quad * 4;
#pragma unroll
        for (int nj = 0; nj < NF; nj++) {
            int col = n0 + wn * (TN / 2) + nj * 16 + lm;
            float bb = bias[col];
#pragma unroll
            for (int rg = 0; rg < 4; rg++) {
                int row = rb + rg;
                if (row < M) {
                    float y = acc[mi][nj][rg] + bb;
                    Co[(size_t)row * NT + col] = f2bf(y);
                    sum += y; ss += y * y;
                }
            }
        }
    }
    rs[t] = sum; rq[t] = ss;
    __syncthreads();
    for (int o = 128; o > 0; o >>= 1) {
        if (t < o) { rs[t] += rs[t + o]; rq[t] += rq[t + o]; }
        __syncthreads();
    }
    if (t == 0) { atomicAdd(&stat[0], rs[0]); atomicAdd(&stat[1], rq[0]); }
}

// ---------------- graph-LN + ReLU, in-place bf16, vectorized x8 --------------
template <int C>
__global__ void k_ln_relu_b(unsigned short* __restrict__ h, int n,
                            const float* __restrict__ st,
                            const float* __restrict__ g, const float* __restrict__ b) {
    typedef unsigned short us8 __attribute__((ext_vector_type(8)));
    float mu = st[0] / (float)n;
    float var = st[1] / (float)n - mu * mu;
    var = var < 0.f ? 0.f : var;
    float inv = 1.0f / (sqrtf(var) + EPSV);
    int i8 = (blockIdx.x * blockDim.x + threadIdx.x) * 8;
    if (i8 >= n) return;
    int c = i8 & (C - 1);
    us8 v = *(const us8*)(h + i8);
    us8 o;
#pragma unroll
    for (int j = 0; j < 8; j++) {
        float y = (bf2f(v[j]) - mu) * inv * g[c + j] + b[c + j];
        o[j] = f2bf(fmaxf(y, 0.f));
    }
    *(us8*)(h + i8) = o;
}

// graph-LN + ReLU + column-sum only (layer 2; h2 not needed afterwards)
__global__ void k_ln_colsum(const unsigned short* __restrict__ h, int n,
                            const float* __restrict__ st,
                            const float* __restrict__ g, const float* __restrict__ b,
                            float* __restrict__ colsum) {
    float mu = st[0] / (float)n;
    float var = st[1] / (float)n - mu * mu;
    var = var < 0.f ? 0.f : var;
    float inv = 1.0f / (sqrtf(var) + EPSV);
    int t = threadIdx.x;
    float gv = g[t], bv = b[t];
    float local = 0.f;
    int stride = gridDim.x * blockDim.x;   // multiple of 256 -> channel == t always
    for (int i = blockIdx.x * blockDim.x + t; i < n; i += stride) {
        float y = (bf2f(h[i]) - mu) * inv * gv + bv;
        local += fmaxf(y, 0.f);
    }
    atomicAdd(&colsum[t], local);
}

// ---------------- head: mean-pool @ Wf + bf -> LN(64) -> relu ----------------
__global__ void k_final(const float* __restrict__ colsum, const float* __restrict__ Wf,
                        const float* __restrict__ bf, const float* __restrict__ gx,
                        const float* __restrict__ bx, float* __restrict__ out) {
    __shared__ float p[256];
    int t = threadIdx.x;
    p[t] = colsum[t] * (1.0f / (float)NODES);
    __syncthreads();
    if (t < 64) {
        float acc = bf[t];
        for (int c = 0; c < 256; c++) acc = fmaf(p[c], Wf[c * 64 + t], acc);
        float sum = acc;
        for (int o = 32; o > 0; o >>= 1) sum += __shfl_xor(sum, o);
        float mu = sum * (1.0f / 64.0f);
        float d = acc - mu;
        float vs = d * d;
        for (int o = 32; o > 0; o >>= 1) vs += __shfl_xor(vs, o);
        float var = vs * (1.0f / 64.0f);
        float y = d * rsqrtf(var + EPSV) * gx[t] + bx[t];
        out[t] = fmaxf(y, 0.f);
    }
}

extern "C" void kernel_launch(void* const* d_in, const int* in_sizes, int n_in,
                              void* d_out, int out_size, void* d_ws, size_t ws_size,
                              hipStream_t stream) {
    const float* x   = (const float*)d_in[0];
    const int*   ei  = (const int*)d_in[1];
    const float* t1  = (const float*)d_in[2];
    const float* Wl1 = (const float*)d_in[3];
    const float* bl1 = (const float*)d_in[4];
    const float* Wr1 = (const float*)d_in[5];
    const float* g1  = (const float*)d_in[6];
    const float* be1 = (const float*)d_in[7];
    const float* t2  = (const float*)d_in[8];
    const float* Wl2 = (const float*)d_in[9];
    const float* bl2 = (const float*)d_in[10];
    const float* Wr2 = (const float*)d_in[11];
    const float* g2  = (const float*)d_in[12];
    const float* be2 = (const float*)d_in[13];
    const float* Wf  = (const float*)d_in[14];
    const float* bf  = (const float*)d_in[15];
    const float* gx  = (const float*)d_in[16];
    const float* bx  = (const float*)d_in[17];
    float* out = (float*)d_out;

    char* ws = (char*)d_ws;
    size_t off = 0;
    auto alloc = [&](size_t bytes) { size_t o = off; off = (off + bytes + 511) & ~511ull; return o; };
    size_t o_counts = alloc((size_t)NODES * 4);
    size_t o_cursor = alloc((size_t)NODES * 4);
    size_t zero_bytes = off;                         // memset: counts+cursor only
    size_t o_acc    = alloc(4 * 4);
    size_t o_colsum = alloc(256 * 4);
    size_t o_offs = alloc((size_t)(NODES + 1) * 4);
    size_t o_csrc = alloc((size_t)EDGES * 4);
    size_t o_w1l  = alloc((size_t)512 * 256 * 2);
    size_t o_w1r  = alloc((size_t)512 * 256 * 2);
    size_t o_w2l  = alloc((size_t)256 * 512 * 2);
    size_t o_w2r  = alloc((size_t)256 * 512 * 2);
    size_t o_bufX = alloc((size_t)MPAD * 256 * 2);   // xb, later h2_pre (bf16)
    size_t o_agg  = alloc((size_t)MPAD * 512 * 2);   // agg1b / agg2b
    size_t o_h1   = alloc((size_t)(MPAD + 512) * 512 * 2); // h1 (+pad-tile slack)

    int*   counts = (int*)(ws + o_counts);
    int*   cursor = (int*)(ws + o_cursor);
    float* acc    = (float*)(ws + o_acc);      // [0,1]=L1 stats, [2,3]=L2 stats
    float* colsum = (float*)(ws + o_colsum);
    int*   offs   = (int*)(ws + o_offs);
    int*   csrc   = (int*)(ws + o_csrc);
    unsigned short* w1lt = (unsigned short*)(ws + o_w1l);
    unsigned short* w1rt = (unsigned short*)(ws + o_w1r);
    unsigned short* w2lt = (unsigned short*)(ws + o_w2l);
    unsigned short* w2rt = (unsigned short*)(ws + o_w2r);
    unsigned short* xb   = (unsigned short*)(ws + o_bufX);
    unsigned short* h2p  = (unsigned short*)(ws + o_bufX);  // reuse after xb dead
    unsigned short* aggb = (unsigned short*)(ws + o_agg);
    unsigned short* h1   = (unsigned short*)(ws + o_h1);

    const int* src = ei;
    const int* dst = ei + EDGES;

    hipMemsetAsync(ws, 0, zero_bytes, stream);

    // D1: fused prep (count + cast + transposes + zero acc/colsum)
    k_prep<<<PREP_TOTAL, 256, 0, stream>>>(dst, counts, x, xb,
                                           Wl1, Wr1, Wl2, Wr2,
                                           w1lt, w1rt, w2lt, w2rt,
                                           acc, colsum);
    // D2/D3: CSR
    k_scan<<<1, 256, 0, stream>>>(counts, offs);
    k_scatter<<<(EDGES + 255) / 256, 256, 0, stream>>>(src, dst, offs, cursor, csrc);

    // ----- layer 1 -----  (2 waves per node, 128 ch each)
    k_agg<256, 2, 8><<<(NODES * 2 + 3) / 4, 256, 0, stream>>>(xb, t1, offs, csrc, aggb);
    k_gemm_mfma<256, 512, 4, 128><<<8 * 4 * 20, 256, 0, stream>>>(
        aggb, w1lt, xb, w1rt, bl1, h1, NODES, acc);
    k_ln_relu_b<512><<<NODES * 512 / 8 / 256, 256, 0, stream>>>(h1, NODES * 512, acc, g1, be1);

    // ----- layer 2 -----  (2 waves per node, 256 ch each)
    k_agg<512, 2, 4><<<(NODES * 2 + 3) / 4, 256, 0, stream>>>(h1, t2, offs, csrc, aggb);
    k_gemm_mfma<512, 256, 2, 128><<<8 * 2 * 20, 256, 0, stream>>>(
        aggb, w2lt, h1, w2rt, bl2, h2p, NODES, acc + 2);

    // ----- LN2 + colsum, then head -----
    k_ln_colsum<<<1024, 256, 0, stream>>>(h2p, NODES * 256, acc + 2, g2, be2, colsum);
    k_final<<<1, 256, 0, stream>>>(colsum, Wf, bf, gx, bx, out);
}